// Round 1
// baseline (504.405 us; speedup 1.0000x reference)
//
#include <hip/hip_runtime.h>
#include <hip/hip_bf16.h>
#include <cstdint>

#define SEQ   1025
#define SPAD  1088
#define DIM   2048
#define NQKV  6144
#define MROWS 4100   // B*SEQ
#define MPAD  4224   // 33*128
#define NH    32

typedef __attribute__((ext_vector_type(8))) short bf16x8;
typedef __attribute__((ext_vector_type(4))) short bf16x4;
typedef __attribute__((ext_vector_type(4))) float f32x4;

#define MFMA16x16(A,B,C) __builtin_amdgcn_mfma_f32_16x16x32_bf16(A,B,C,0,0,0)

static __device__ __forceinline__ float bf2f(short s) {
    union { unsigned int u; float f; } v;
    v.u = ((unsigned int)(unsigned short)s) << 16;
    return v.f;
}
static __device__ __forceinline__ short f2bf(float f) {
    union { float f; unsigned int u; } v; v.f = f;
    unsigned int r = v.u + 0x7fffu + ((v.u >> 16) & 1u);
    return (short)(r >> 16);
}

typedef __attribute__((address_space(1))) unsigned int u32g;
typedef __attribute__((address_space(3))) unsigned int u32l;
// LDS dest is wave-uniform base; HW adds lane*16 (guide §5, m104/m108).
static __device__ __forceinline__ void gld_lds16(void* lds, const void* g) {
    __builtin_amdgcn_global_load_lds((const u32g*)(uintptr_t)g,
                                     (u32l*)(uintptr_t)lds, 16, 0, 0);
}

// ---------------- RoPE cos/sin table: theta[s][f], f in [0,32) ----------------
__global__ __launch_bounds__(256) void trig_k(float* __restrict__ cosT, float* __restrict__ sinT) {
    int i = blockIdx.x * 256 + threadIdx.x;
    if (i >= SEQ * 16) return;
    int s = i >> 4, f = i & 15;
    float ph = 0.f, pw = 0.f;
    if (s > 0) {
        int p = s - 1;
        ph = -1.f + ((p >> 5) + 0.5f) * 0.0625f;
        pw = -1.f + ((p & 31) + 0.5f) * 0.0625f;
    }
    // freqs = pi * 10^(f/15)
    double fr = 3.141592653589793 * exp((double)f * 0.15350567286626973);
    float th = (float)(ph * fr), tw = (float)(pw * fr);
    cosT[s*32 + f]      = cosf(th);
    sinT[s*32 + f]      = sinf(th);
    cosT[s*32 + 16 + f] = cosf(tw);
    sinT[s*32 + 16 + f] = sinf(tw);
}

// ---------------- RMSNorm fp32 -> bf16, rows >= MROWS zero-filled ----------------
__global__ __launch_bounds__(256) void rmsnorm_k(const float* __restrict__ x,
                                                 const float* __restrict__ sc,
                                                 short* __restrict__ h) {
    int row = blockIdx.x, t = threadIdx.x;
    short* hr = h + (size_t)row * DIM;
    if (row >= MROWS) {
        bf16x8 z = {};
        *(bf16x8*)(hr + t*8) = z;
        return;
    }
    const float4* xr = (const float4*)(x + (size_t)row * DIM);
    float4 a = xr[2*t], b = xr[2*t+1];
    float ss = a.x*a.x + a.y*a.y + a.z*a.z + a.w*a.w
             + b.x*b.x + b.y*b.y + b.z*b.z + b.w*b.w;
    #pragma unroll
    for (int off = 32; off; off >>= 1) ss += __shfl_xor(ss, off, 64);
    __shared__ float red[4];
    if ((t & 63) == 0) red[t >> 6] = ss;
    __syncthreads();
    float ms = (red[0]+red[1]+red[2]+red[3]) * (1.0f/2048.0f);
    float inv = rsqrtf(ms + 1e-6f);
    const float4* sr = (const float4*)sc;
    float4 s0 = sr[2*t], s1 = sr[2*t+1];
    bf16x8 o;
    o[0]=f2bf(a.x*(s0.x*inv)); o[1]=f2bf(a.y*(s0.y*inv));
    o[2]=f2bf(a.z*(s0.z*inv)); o[3]=f2bf(a.w*(s0.w*inv));
    o[4]=f2bf(b.x*(s1.x*inv)); o[5]=f2bf(b.y*(s1.y*inv));
    o[6]=f2bf(b.z*(s1.z*inv)); o[7]=f2bf(b.w*(s1.w*inv));
    *(bf16x8*)(hr + t*8) = o;
}

// ---------------- fp32 -> bf16 weight conversion ----------------
__global__ __launch_bounds__(256) void conv_k(const float* __restrict__ in, short* __restrict__ o, int n4) {
    int i = blockIdx.x * 256 + threadIdx.x;
    if (i >= n4) return;
    float4 v = ((const float4*)in)[i];
    bf16x4 r = { f2bf(v.x), f2bf(v.y), f2bf(v.z), f2bf(v.w) };
    *(bf16x4*)(o + (size_t)i*4) = r;
}

// ---------------- GEMM: C[m,n] = sum_k A[m,k]*B[n,k] (both K-inner, bf16) ------
// m97 structure: 128x128 tile, BK=32, 4 waves x (64x64), global_load_lds w=16.
template<int WRITE_BF16>
__global__ __launch_bounds__(256) void gemm_bt(const short* __restrict__ A,
                                               const short* __restrict__ B,
                                               void* __restrict__ C,
                                               const float* __restrict__ skip,
                                               int N, int K) {
    __shared__ short As[128*32];
    __shared__ short Bs[128*32];
    const int bm = blockIdx.x, bn = blockIdx.y;
    const int t = threadIdx.x;
    const int w = t >> 6, l = t & 63;
    const int lr = l & 15, lg = l >> 4;
    const int wr = w >> 1, wc = w & 1;
    const short* Ab = A + (size_t)bm * 128 * K;
    const short* Bb = B + (size_t)bn * 128 * K;

    f32x4 acc[4][4] = {};

    const int c1 = t + 256;
    const int ar0 = t >> 2,  ac0 = (t & 3) * 8;
    const int ar1 = c1 >> 2, ac1 = (c1 & 3) * 8;

    for (int k0 = 0; k0 < K; k0 += 32) {
        gld_lds16((char*)As + (w << 10),        Ab + (size_t)ar0 * K + k0 + ac0);
        gld_lds16((char*)As + 4096 + (w << 10), Ab + (size_t)ar1 * K + k0 + ac1);
        gld_lds16((char*)Bs + (w << 10),        Bb + (size_t)ar0 * K + k0 + ac0);
        gld_lds16((char*)Bs + 4096 + (w << 10), Bb + (size_t)ar1 * K + k0 + ac1);
        __syncthreads();
        bf16x8 af[4], bfv[4];
        #pragma unroll
        for (int m = 0; m < 4; ++m)
            af[m] = *(const bf16x8*)(As + (wr*64 + m*16 + lr)*32 + lg*8);
        #pragma unroll
        for (int n = 0; n < 4; ++n)
            bfv[n] = *(const bf16x8*)(Bs + (wc*64 + n*16 + lr)*32 + lg*8);
        #pragma unroll
        for (int m = 0; m < 4; ++m)
            #pragma unroll
            for (int n = 0; n < 4; ++n)
                acc[m][n] = MFMA16x16(af[m], bfv[n], acc[m][n]);
        __syncthreads();
    }

    #pragma unroll
    for (int m = 0; m < 4; ++m) {
        const int row0 = bm*128 + wr*64 + m*16 + lg*4;
        #pragma unroll
        for (int n = 0; n < 4; ++n) {
            const int col = bn*128 + wc*64 + n*16 + lr;
            #pragma unroll
            for (int r = 0; r < 4; ++r) {
                const int row = row0 + r;
                if constexpr (WRITE_BF16) {
                    ((short*)C)[(size_t)row * N + col] = f2bf(acc[m][n][r]);
                } else {
                    if (row < MROWS)
                        ((float*)C)[(size_t)row * N + col] =
                            acc[m][n][r] + skip[(size_t)row * N + col];
                }
            }
        }
    }
}

// ---------------- K RoPE + scatter to (bh,SPAD,64); V transpose to (bh,64,SPAD) --
__global__ __launch_bounds__(256) void rearrange_k(const short* __restrict__ qkv,
        const float* __restrict__ cosT, const float* __restrict__ sinT,
        short* __restrict__ kr, short* __restrict__ vt) {
    int bid = blockIdx.x;
    int bh = bid / 17, st = bid % 17;
    int b = bh >> 5, hh = bh & 31;
    int s0 = st * 64;
    int t = threadIdx.x;
    __shared__ short vs[64][68];
    #pragma unroll
    for (int i = 0; i < 8; ++i) {
        int task = t + i*256;
        int sl = task >> 5, p = task & 31;
        int s = s0 + sl;
        float y1 = 0.f, y2 = 0.f;
        if (s < SEQ) {
            const short* src = qkv + (size_t)(b*SEQ + s)*NQKV + DIM + hh*64;
            float x1 = bf2f(src[p]), x2 = bf2f(src[32+p]);
            float c = cosT[s*32+p], sn = sinT[s*32+p];
            y1 = x1*c - x2*sn;
            y2 = x2*c + x1*sn;
        }
        short* dst = kr + ((size_t)bh*SPAD + s)*64;
        dst[p]    = f2bf(y1);
        dst[32+p] = f2bf(y2);
    }
    #pragma unroll
    for (int i = 0; i < 16; ++i) {
        int task = t + i*256;
        int sl = task >> 6, d = task & 63;
        int s = s0 + sl;
        short v = 0;
        if (s < SEQ) v = qkv[(size_t)(b*SEQ + s)*NQKV + 2*DIM + hh*64 + d];
        vs[sl][d] = v;
    }
    __syncthreads();
    #pragma unroll
    for (int i = 0; i < 16; ++i) {
        int task = t + i*256;
        int d = task >> 6, sl = task & 63;
        vt[((size_t)bh*64 + d)*SPAD + s0 + sl] = vs[sl][d];
    }
}

// ---------------- Flash attention: 64 q-rows/block, 4 waves x 16 rows ----------
// Swapped QK^T (S^T = mfma(K,Q)) so softmax is a column reduce (2 shuffles) and
// P-frag is built lane-locally. K tile XOR-swizzled (G4) via pre-swizzled global
// source (rule #21); V^T tile likewise (64B rows).
__global__ __launch_bounds__(256) void attn_k(const short* __restrict__ qkv,
        const short* __restrict__ kr, const short* __restrict__ vt,
        const float* __restrict__ cosT, const float* __restrict__ sinT,
        short* __restrict__ ob) {
    const int bh = blockIdx.y;
    const int b = bh >> 5, hh = bh & 31;
    const int q0 = blockIdx.x * 64;
    const int t = threadIdx.x, w = t >> 6, l = t & 63;
    const int lr = l & 15, lg = l >> 4;

    __shared__ short Ks[32*64];
    __shared__ short Vts[64*32];

    const int qrow = q0 + w*16 + lr;
    const int qc = qrow < SEQ ? qrow : SEQ-1;
    const short* qsrc = qkv + (size_t)(b*SEQ + qc)*NQKV + hh*64;
    bf16x8 xlo = *(const bf16x8*)(qsrc + lg*8);
    bf16x8 xhi = *(const bf16x8*)(qsrc + 32 + lg*8);
    const float4* cp = (const float4*)(cosT + qc*32 + lg*8);
    const float4* sp = (const float4*)(sinT + qc*32 + lg*8);
    float cc[8], sn[8];
    { float4 u = cp[0], v2 = cp[1];
      cc[0]=u.x; cc[1]=u.y; cc[2]=u.z; cc[3]=u.w;
      cc[4]=v2.x; cc[5]=v2.y; cc[6]=v2.z; cc[7]=v2.w; }
    { float4 u = sp[0], v2 = sp[1];
      sn[0]=u.x; sn[1]=u.y; sn[2]=u.z; sn[3]=u.w;
      sn[4]=v2.x; sn[5]=v2.y; sn[6]=v2.z; sn[7]=v2.w; }
    bf16x8 qf0, qf1;
    #pragma unroll
    for (int j = 0; j < 8; ++j) {
        float x1 = bf2f(xlo[j]), x2 = bf2f(xhi[j]);
        qf0[j] = f2bf(x1*cc[j] - x2*sn[j]);
        qf1[j] = f2bf(x2*cc[j] + x1*sn[j]);
    }

    f32x4 oacc[4] = {};
    float mrun = -1e30f, lrun = 0.f;
    const int ntile = min((q0 + 64 + 31) >> 5, 33);
    const float SC = 0.125f * 1.4426950408889634f;  // /sqrt(64) * log2(e)

    const short* kbase = kr + (size_t)bh * SPAD * 64;
    const short* vbase = vt + (size_t)bh * 64 * SPAD;

    const int skrow = t >> 3, skslot = t & 7;
    const int svrow = t >> 2, svslot = t & 3;

    for (int kt = 0; kt < ntile; ++kt) {
        const int kv0 = kt * 32;
        gld_lds16((char*)Ks + (w<<10),
                  (const char*)(kbase + (size_t)(kv0 + skrow)*64) + ((skslot ^ (skrow & 7)) << 4));
        gld_lds16((char*)Vts + (w<<10),
                  (const char*)(vbase + (size_t)svrow*SPAD + kv0) + ((svslot ^ ((svrow>>1) & 3)) << 4));
        __syncthreads();

        f32x4 st0 = {}, st1 = {};
        {
            const int krow = lr;
            const int swz = (krow & 7) << 4;
            const char* kp = (const char*)Ks + krow*128;
            bf16x8 a0 = *(const bf16x8*)(kp + ((lg*16) ^ swz));
            bf16x8 a1 = *(const bf16x8*)(kp + ((64 + lg*16) ^ swz));
            st0 = MFMA16x16(a0, qf0, st0);
            st0 = MFMA16x16(a1, qf1, st0);
        }
        {
            const int krow = 16 + lr;
            const int swz = (krow & 7) << 4;
            const char* kp = (const char*)Ks + krow*128;
            bf16x8 a0 = *(const bf16x8*)(kp + ((lg*16) ^ swz));
            bf16x8 a1 = *(const bf16x8*)(kp + ((64 + lg*16) ^ swz));
            st1 = MFMA16x16(a0, qf0, st1);
            st1 = MFMA16x16(a1, qf1, st1);
        }

        float sv[8];
        float tmax = -1e30f;
        #pragma unroll
        for (int r = 0; r < 4; ++r) {
            int kv = kv0 + lg*4 + r;
            float v = st0[r] * SC;
            v = (kv <= qrow && kv < SEQ) ? v : -1e30f;
            sv[r] = v; tmax = fmaxf(tmax, v);
        }
        #pragma unroll
        for (int r = 0; r < 4; ++r) {
            int kv = kv0 + 16 + lg*4 + r;
            float v = st1[r] * SC;
            v = (kv <= qrow && kv < SEQ) ? v : -1e30f;
            sv[4+r] = v; tmax = fmaxf(tmax, v);
        }
        tmax = fmaxf(tmax, __shfl_xor(tmax, 16, 64));
        tmax = fmaxf(tmax, __shfl_xor(tmax, 32, 64));
        float mnew = fmaxf(mrun, tmax);
        float alpha = exp2f(mrun - mnew);
        float psum = 0.f;
        bf16x8 pf;
        #pragma unroll
        for (int i2 = 0; i2 < 8; ++i2) {
            float p = exp2f(sv[i2] - mnew);
            psum += p;
            pf[i2] = f2bf(p);
        }
        psum += __shfl_xor(psum, 16, 64);
        psum += __shfl_xor(psum, 32, 64);
        lrun = lrun * alpha + psum;
        mrun = mnew;
        #pragma unroll
        for (int df = 0; df < 4; ++df) {
            oacc[df][0] *= alpha; oacc[df][1] *= alpha;
            oacc[df][2] *= alpha; oacc[df][3] *= alpha;
        }
        #pragma unroll
        for (int df = 0; df < 4; ++df) {
            const int vrow = df*16 + lr;
            const int swz = ((vrow >> 1) & 3) << 4;
            const char* vp = (const char*)Vts + vrow*64;
            bf16x4 v0 = *(const bf16x4*)(vp + ((lg*8) ^ swz));
            bf16x4 v1 = *(const bf16x4*)(vp + ((32 + lg*8) ^ swz));
            bf16x8 vf;
            vf[0]=v0[0]; vf[1]=v0[1]; vf[2]=v0[2]; vf[3]=v0[3];
            vf[4]=v1[0]; vf[5]=v1[1]; vf[6]=v1[2]; vf[7]=v1[3];
            oacc[df] = MFMA16x16(vf, pf, oacc[df]);
        }
        __syncthreads();
    }

    if (qrow < SEQ) {
        float inv = 1.0f / lrun;
        short* orow = ob + (size_t)(b*SEQ + qrow)*DIM + hh*64;
        #pragma unroll
        for (int df = 0; df < 4; ++df) {
            bf16x4 ov = { f2bf(oacc[df][0]*inv), f2bf(oacc[df][1]*inv),
                          f2bf(oacc[df][2]*inv), f2bf(oacc[df][3]*inv) };
            *(bf16x4*)(orow + df*16 + lg*4) = ov;
        }
    }
}

extern "C" void kernel_launch(void* const* d_in, const int* in_sizes, int n_in,
                              void* d_out, int out_size, void* d_ws, size_t ws_size,
                              hipStream_t stream) {
    const float* x     = (const float*)d_in[0];
    const float* scale = (const float*)d_in[1];
    const float* w_qkv = (const float*)d_in[2];
    const float* w_out = (const float*)d_in[3];
    float* out = (float*)d_out;

    char* ws = (char*)d_ws;
    size_t off = 0;
    auto alloc = [&](size_t bytes) -> char* {
        char* p = ws + off;
        off += (bytes + 255) & ~(size_t)255;
        return p;
    };
    float* cosT  = (float*)alloc((size_t)SEQ*32*4);
    float* sinT  = (float*)alloc((size_t)SEQ*32*4);
    short* h_b   = (short*)alloc((size_t)MPAD*DIM*2);   // reused as o_b after GEMM1
    short* wq_b  = (short*)alloc((size_t)NQKV*DIM*2);
    short* wo_b  = (short*)alloc((size_t)DIM*DIM*2);
    short* qkv_b = (short*)alloc((size_t)MPAD*NQKV*2);
    short* k_r   = (short*)alloc((size_t)128*SPAD*64*2);
    short* vt    = (short*)alloc((size_t)128*SPAD*64*2);
    short* o_b   = h_b;  // pad rows of h are zeros and stay zeros

    trig_k<<<65, 256, 0, stream>>>(cosT, sinT);
    rmsnorm_k<<<MPAD, 256, 0, stream>>>(x, scale, h_b);
    conv_k<<<(NQKV*DIM/4 + 255)/256, 256, 0, stream>>>(w_qkv, wq_b, NQKV*DIM/4);
    conv_k<<<(DIM*DIM/4 + 255)/256, 256, 0, stream>>>(w_out, wo_b, DIM*DIM/4);
    gemm_bt<1><<<dim3(33,48), 256, 0, stream>>>(h_b, wq_b, qkv_b, nullptr, NQKV, DIM);
    rearrange_k<<<128*17, 256, 0, stream>>>(qkv_b, cosT, sinT, k_r, vt);
    attn_k<<<dim3(17,128), 256, 0, stream>>>(qkv_b, k_r, vt, cosT, sinT, o_b);
    gemm_bt<0><<<dim3(33,16), 256, 0, stream>>>(o_b, wo_b, out, x, DIM, DIM);
}

// Round 2
// 467.152 us; speedup vs baseline: 1.0797x; 1.0797x over previous
//
#include <hip/hip_runtime.h>
#include <hip/hip_bf16.h>
#include <cstdint>

#define SEQ   1025
#define SPAD  1088
#define DIM   2048
#define NQKV  6144
#define MROWS 4100   // B*SEQ
#define MPAD  4352   // 17*256
#define NH    32

typedef __attribute__((ext_vector_type(8))) short bf16x8;
typedef __attribute__((ext_vector_type(4))) short bf16x4;
typedef __attribute__((ext_vector_type(4))) float f32x4;

#define MFMA16x16(A,B,C) __builtin_amdgcn_mfma_f32_16x16x32_bf16(A,B,C,0,0,0)

static __device__ __forceinline__ float bf2f(short s) {
    union { unsigned int u; float f; } v;
    v.u = ((unsigned int)(unsigned short)s) << 16;
    return v.f;
}
static __device__ __forceinline__ short f2bf(float f) {
    union { float f; unsigned int u; } v; v.f = f;
    unsigned int r = v.u + 0x7fffu + ((v.u >> 16) & 1u);
    return (short)(r >> 16);
}

typedef __attribute__((address_space(1))) unsigned int u32g;
typedef __attribute__((address_space(3))) unsigned int u32l;
// LDS dest is wave-uniform base; HW adds lane*16 (m104/m108).
static __device__ __forceinline__ void gld_lds16(void* lds, const void* g) {
    __builtin_amdgcn_global_load_lds((const u32g*)(uintptr_t)g,
                                     (u32l*)(uintptr_t)lds, 16, 0, 0);
}

#define SBX() __builtin_amdgcn_sched_barrier(0)
#define PRIO(x) __builtin_amdgcn_s_setprio(x)

// ---------------- RoPE cos/sin table: theta[s][f], f in [0,32) ----------------
__global__ __launch_bounds__(256) void trig_k(float* __restrict__ cosT, float* __restrict__ sinT) {
    int i = blockIdx.x * 256 + threadIdx.x;
    if (i >= SEQ * 16) return;
    int s = i >> 4, f = i & 15;
    float ph = 0.f, pw = 0.f;
    if (s > 0) {
        int p = s - 1;
        ph = -1.f + ((p >> 5) + 0.5f) * 0.0625f;
        pw = -1.f + ((p & 31) + 0.5f) * 0.0625f;
    }
    // freqs = pi * 10^(f/15)
    double fr = 3.141592653589793 * exp((double)f * 0.15350567286626973);
    float th = (float)(ph * fr), tw = (float)(pw * fr);
    cosT[s*32 + f]      = cosf(th);
    sinT[s*32 + f]      = sinf(th);
    cosT[s*32 + 16 + f] = cosf(tw);
    sinT[s*32 + 16 + f] = sinf(tw);
}

// ---------------- RMSNorm fp32 -> bf16, rows >= MROWS zero-filled ----------------
__global__ __launch_bounds__(256) void rmsnorm_k(const float* __restrict__ x,
                                                 const float* __restrict__ sc,
                                                 short* __restrict__ h) {
    int row = blockIdx.x, t = threadIdx.x;
    short* hr = h + (size_t)row * DIM;
    if (row >= MROWS) {
        bf16x8 z = {};
        *(bf16x8*)(hr + t*8) = z;
        return;
    }
    const float4* xr = (const float4*)(x + (size_t)row * DIM);
    float4 a = xr[2*t], b = xr[2*t+1];
    float ss = a.x*a.x + a.y*a.y + a.z*a.z + a.w*a.w
             + b.x*b.x + b.y*b.y + b.z*b.z + b.w*b.w;
    #pragma unroll
    for (int off = 32; off; off >>= 1) ss += __shfl_xor(ss, off, 64);
    __shared__ float red[4];
    if ((t & 63) == 0) red[t >> 6] = ss;
    __syncthreads();
    float ms = (red[0]+red[1]+red[2]+red[3]) * (1.0f/2048.0f);
    float inv = rsqrtf(ms + 1e-6f);
    const float4* sr = (const float4*)sc;
    float4 s0 = sr[2*t], s1 = sr[2*t+1];
    bf16x8 o;
    o[0]=f2bf(a.x*(s0.x*inv)); o[1]=f2bf(a.y*(s0.y*inv));
    o[2]=f2bf(a.z*(s0.z*inv)); o[3]=f2bf(a.w*(s0.w*inv));
    o[4]=f2bf(b.x*(s1.x*inv)); o[5]=f2bf(b.y*(s1.y*inv));
    o[6]=f2bf(b.z*(s1.z*inv)); o[7]=f2bf(b.w*(s1.w*inv));
    *(bf16x8*)(hr + t*8) = o;
}

// ---------------- fp32 -> bf16 weight conversion ----------------
__global__ __launch_bounds__(256) void conv_k(const float* __restrict__ in, short* __restrict__ o, int n4) {
    int i = blockIdx.x * 256 + threadIdx.x;
    if (i >= n4) return;
    float4 v = ((const float4*)in)[i];
    bf16x4 r = { f2bf(v.x), f2bf(v.y), f2bf(v.z), f2bf(v.w) };
    *(bf16x4*)(o + (size_t)i*4) = r;
}

// ================= 8-phase 256x256 GEMM (m201 template, re-derived) ===========
// C[m,n] = sum_k A[m,k]*B[n,k], A/B K-inner bf16, C bf16.
// 512 thr = 8 waves (2M x 4N), BK=64, LDS 2 x (A 32KB + B 32KB) = 128KB dynamic.
// LDS tiles [256 rows][128B] with XOR swizzle byte^=(row&7)<<4 applied on BOTH
// sides: inverse-swizzled global source for global_load_lds (linear dest) and
// swizzled ds_read addresses (rule #21).  Schedule per K-tile (4 phases):
//   ph0: ds_read A-half0(8) + B n0,1(4); bar; lgkm0; 16 MFMA q(0,0); bar
//   ph1: ds_read B n2,3(4);              bar; lgkm0; 16 MFMA q(0,1); bar
//   ph2: ds_read A-half1(8);             bar; lgkm0; 16 MFMA q(1,1); bar
//   ph3: stage next tile into this buf (8 gld); bar; 16 MFMA q(1,0);
//        vmcnt(8) [counted: 8 newest = other buf's stage, oldest 8 done]; bar
// Race-freedom: each phase's ds_reads are drained (lgkmcnt0) before its closing
// barrier, so staging DMA into that buffer (issued after the barrier, ph3/ph7)
// never overlaps in-flight reads; vmcnt(8)+barrier orders DMA completion
// (per-wave counter) against ALL waves' subsequent reads.
__global__ __launch_bounds__(512, 2) void gemm8p(const short* __restrict__ A,
                                                 const short* __restrict__ B,
                                                 short* __restrict__ C,
                                                 int N, int K, int nbm) {
    extern __shared__ char smem[];
    const int nwg = gridDim.x;            // multiple of 8
    const int cpx = nwg >> 3;
    const int bid = blockIdx.x;
    const int sid = (bid & 7) * cpx + (bid >> 3);   // T1 XCD swizzle (bijective)
    const int bm = sid % nbm;
    const int bn = sid / nbm;

    const int t = threadIdx.x, w = t >> 6, l = t & 63;
    const int lr = l & 15, lg = l >> 4;
    const int wr = w >> 2, wc = w & 3;    // 2M x 4N wave grid

    const short* Ab = A + (size_t)bm * 256 * K;
    const short* Bb = B + (size_t)bn * 256 * K;

    // staging: thread t covers LDS bytes [t*16, t*16+16) of each 8KB chunk
    // (chunk = 64 rows x 128B); row R = c*64 + t/8; source col pre-swizzled.
    const int srow = t >> 3;
    const int scol = (((t & 7) ^ (srow & 7)) << 3);   // element offset in row

    // read-side swizzled col offsets (bytes within 128B row), kk = 0,1
    const int cs0 = (lg * 16) ^ ((lr & 7) << 4);
    const int cs1 = (64 + lg * 16) ^ ((lr & 7) << 4);
    const int aRowB = (wr * 128 + lr) * 128;   // + h*8192 + am*2048
    const int bRowB = (wc * 64 + lr) * 128;    // + n*2048

    f32x4 acc[8][4] = {};
    bf16x8 rA[4][2], rB[4][2];

#define STAGE8(kt, bb) do {                                                   \
    const int k0_ = (kt) * 64;                                                \
    _Pragma("unroll")                                                         \
    for (int c = 0; c < 4; ++c) {                                             \
        gld_lds16(smem + (bb)*65536 + c*8192 + (w<<10),                       \
                  Ab + (size_t)(c*64 + srow) * K + k0_ + scol);               \
        gld_lds16(smem + (bb)*65536 + 32768 + c*8192 + (w<<10),               \
                  Bb + (size_t)(c*64 + srow) * K + k0_ + scol);               \
    }                                                                         \
} while (0)

#define READ_A8(bb, h) do {                                                   \
    const char* p_ = smem + (bb)*65536 + aRowB + (h)*8192;                    \
    _Pragma("unroll")                                                         \
    for (int am = 0; am < 4; ++am) {                                          \
        rA[am][0] = *(const bf16x8*)(p_ + am*2048 + cs0);                     \
        rA[am][1] = *(const bf16x8*)(p_ + am*2048 + cs1);                     \
    }                                                                         \
} while (0)

#define READ_B4(bb, np) do {                                                  \
    const char* p_ = smem + (bb)*65536 + 32768 + bRowB + (np)*4096;           \
    _Pragma("unroll")                                                         \
    for (int nn = 0; nn < 2; ++nn) {                                          \
        rB[(np)*2+nn][0] = *(const bf16x8*)(p_ + nn*2048 + cs0);              \
        rB[(np)*2+nn][1] = *(const bf16x8*)(p_ + nn*2048 + cs1);              \
    }                                                                         \
} while (0)

#define MF_Q(h, nh) do {                                                      \
    _Pragma("unroll")                                                         \
    for (int am = 0; am < 4; ++am)                                            \
    _Pragma("unroll")                                                         \
    for (int nn = 0; nn < 2; ++nn) {                                          \
        acc[(h)*4+am][(nh)*2+nn] =                                            \
            MFMA16x16(rA[am][0], rB[(nh)*2+nn][0], acc[(h)*4+am][(nh)*2+nn]); \
        acc[(h)*4+am][(nh)*2+nn] =                                            \
            MFMA16x16(rA[am][1], rB[(nh)*2+nn][1], acc[(h)*4+am][(nh)*2+nn]); \
    }                                                                         \
} while (0)

#define PH_COMPUTE(h, nh) do {                                                \
    SBX(); __builtin_amdgcn_s_barrier();                                      \
    asm volatile("s_waitcnt lgkmcnt(0)" ::: "memory"); SBX();                 \
    PRIO(1); MF_Q(h, nh); PRIO(0); SBX();                                     \
    __builtin_amdgcn_s_barrier(); SBX();                                      \
} while (0)

    STAGE8(0, 0);
    STAGE8(1, 1);
    asm volatile("s_waitcnt vmcnt(8)" ::: "memory"); SBX();
    __builtin_amdgcn_s_barrier(); SBX();

    const int NT2 = K / 128;   // iterations, 2 K-tiles each
    for (int it = 0; it < NT2; ++it) {
        const bool more = (it < NT2 - 1);
        // ---- K-tile 2it from buf0 ----
        READ_A8(0, 0); READ_B4(0, 0); PH_COMPUTE(0, 0);          // ph0
        READ_B4(0, 1);                PH_COMPUTE(0, 1);          // ph1
        READ_A8(0, 1);                PH_COMPUTE(1, 1);          // ph2
        // ph3: stage tile 2it+2 -> buf0, MFMA q(1,0), counted vmcnt
        if (more) STAGE8(2*it + 2, 0);
        SBX(); __builtin_amdgcn_s_barrier(); SBX();
        PRIO(1); MF_Q(1, 0); PRIO(0); SBX();
        if (more) { asm volatile("s_waitcnt vmcnt(8)" ::: "memory"); }
        else      { asm volatile("s_waitcnt vmcnt(0)" ::: "memory"); }
        SBX(); __builtin_amdgcn_s_barrier(); SBX();
        // ---- K-tile 2it+1 from buf1 ----
        READ_A8(1, 0); READ_B4(1, 0); PH_COMPUTE(0, 0);          // ph4
        READ_B4(1, 1);                PH_COMPUTE(0, 1);          // ph5
        READ_A8(1, 1);                PH_COMPUTE(1, 1);          // ph6
        // ph7: stage tile 2it+3 -> buf1, MFMA q(1,0), counted vmcnt
        if (more) STAGE8(2*it + 3, 1);
        SBX(); __builtin_amdgcn_s_barrier(); SBX();
        PRIO(1); MF_Q(1, 0); PRIO(0); SBX();
        if (more) { asm volatile("s_waitcnt vmcnt(8)" ::: "memory"); SBX(); }
        __builtin_amdgcn_s_barrier(); SBX();
    }

    // epilogue: C row = bm*256 + wr*128 + m*16 + lg*4 + r, col = bn*256 + wc*64 + n*16 + lr
    #pragma unroll
    for (int m = 0; m < 8; ++m) {
        const int row0 = bm*256 + wr*128 + m*16 + lg*4;
        #pragma unroll
        for (int n = 0; n < 4; ++n) {
            const int col = bn*256 + wc*64 + n*16 + lr;
            #pragma unroll
            for (int r = 0; r < 4; ++r)
                C[(size_t)(row0 + r) * N + col] = f2bf(acc[m][n][r]);
        }
    }
#undef STAGE8
#undef READ_A8
#undef READ_B4
#undef MF_Q
#undef PH_COMPUTE
}

// ---------------- GEMM (m97 structure) for out-proj: fp32 out + skip ----------
__global__ __launch_bounds__(256) void gemm_bt(const short* __restrict__ A,
                                               const short* __restrict__ B,
                                               float* __restrict__ C,
                                               const float* __restrict__ skip,
                                               int N, int K, int nbm) {
    __shared__ short As[128*32];
    __shared__ short Bs[128*32];
    const int nwg = gridDim.x;
    const int cpx = nwg >> 3;
    const int bid = blockIdx.x;
    const int sid = (bid & 7) * cpx + (bid >> 3);   // T1 XCD swizzle
    const int bm = sid % nbm, bn = sid / nbm;
    const int t = threadIdx.x;
    const int w = t >> 6, l = t & 63;
    const int lr = l & 15, lg = l >> 4;
    const int wr = w >> 1, wc = w & 1;
    const short* Ab = A + (size_t)bm * 128 * K;
    const short* Bb = B + (size_t)bn * 128 * K;

    f32x4 acc[4][4] = {};

    const int c1 = t + 256;
    const int ar0 = t >> 2,  ac0 = (t & 3) * 8;
    const int ar1 = c1 >> 2, ac1 = (c1 & 3) * 8;

    for (int k0 = 0; k0 < K; k0 += 32) {
        gld_lds16((char*)As + (w << 10),        Ab + (size_t)ar0 * K + k0 + ac0);
        gld_lds16((char*)As + 4096 + (w << 10), Ab + (size_t)ar1 * K + k0 + ac1);
        gld_lds16((char*)Bs + (w << 10),        Bb + (size_t)ar0 * K + k0 + ac0);
        gld_lds16((char*)Bs + 4096 + (w << 10), Bb + (size_t)ar1 * K + k0 + ac1);
        __syncthreads();
        bf16x8 af[4], bfv[4];
        #pragma unroll
        for (int m = 0; m < 4; ++m)
            af[m] = *(const bf16x8*)(As + (wr*64 + m*16 + lr)*32 + lg*8);
        #pragma unroll
        for (int n = 0; n < 4; ++n)
            bfv[n] = *(const bf16x8*)(Bs + (wc*64 + n*16 + lr)*32 + lg*8);
        #pragma unroll
        for (int m = 0; m < 4; ++m)
            #pragma unroll
            for (int n = 0; n < 4; ++n)
                acc[m][n] = MFMA16x16(af[m], bfv[n], acc[m][n]);
        __syncthreads();
    }

    #pragma unroll
    for (int m = 0; m < 4; ++m) {
        const int row0 = bm*128 + wr*64 + m*16 + lg*4;
        #pragma unroll
        for (int n = 0; n < 4; ++n) {
            const int col = bn*128 + wc*64 + n*16 + lr;
            #pragma unroll
            for (int r = 0; r < 4; ++r) {
                const int row = row0 + r;
                if (row < MROWS)
                    C[(size_t)row * N + col] =
                        acc[m][n][r] + skip[(size_t)row * N + col];
            }
        }
    }
}

// ---------------- K RoPE + scatter to (bh,SPAD,64); V transpose to (bh,64,SPAD) --
__global__ __launch_bounds__(256) void rearrange_k(const short* __restrict__ qkv,
        const float* __restrict__ cosT, const float* __restrict__ sinT,
        short* __restrict__ kr, short* __restrict__ vt) {
    int bid = blockIdx.x;
    int bh = bid / 17, st = bid % 17;
    int b = bh >> 5, hh = bh & 31;
    int s0 = st * 64;
    int t = threadIdx.x;
    __shared__ short vs[64][68];
    #pragma unroll
    for (int i = 0; i < 8; ++i) {
        int task = t + i*256;
        int sl = task >> 5, p = task & 31;
        int s = s0 + sl;
        float y1 = 0.f, y2 = 0.f;
        if (s < SEQ) {
            const short* src = qkv + (size_t)(b*SEQ + s)*NQKV + DIM + hh*64;
            float x1 = bf2f(src[p]), x2 = bf2f(src[32+p]);
            float c = cosT[s*32+p], sn = sinT[s*32+p];
            y1 = x1*c - x2*sn;
            y2 = x2*c + x1*sn;
        }
        short* dst = kr + ((size_t)bh*SPAD + s)*64;
        dst[p]    = f2bf(y1);
        dst[32+p] = f2bf(y2);
    }
    #pragma unroll
    for (int i = 0; i < 16; ++i) {
        int task = t + i*256;
        int sl = task >> 6, d = task & 63;
        int s = s0 + sl;
        short v = 0;
        if (s < SEQ) v = qkv[(size_t)(b*SEQ + s)*NQKV + 2*DIM + hh*64 + d];
        vs[sl][d] = v;
    }
    __syncthreads();
    #pragma unroll
    for (int i = 0; i < 16; ++i) {
        int task = t + i*256;
        int d = task >> 6, sl = task & 63;
        vt[((size_t)bh*64 + d)*SPAD + s0 + sl] = vs[sl][d];
    }
}

// ---------------- Flash attention: 64 q-rows/block, 4 waves x 16 rows ----------
__global__ __launch_bounds__(256) void attn_k(const short* __restrict__ qkv,
        const short* __restrict__ kr, const short* __restrict__ vt,
        const float* __restrict__ cosT, const float* __restrict__ sinT,
        short* __restrict__ ob) {
    const int nwg = gridDim.x;              // 2176, multiple of 8
    const int cpx = nwg >> 3;
    const int bid = blockIdx.x;
    const int sid = (bid & 7) * cpx + (bid >> 3);   // T1: blocks sharing bh -> same XCD
    const int bh = sid / 17;
    const int q0 = (sid % 17) * 64;
    const int b = bh >> 5, hh = bh & 31;
    const int t = threadIdx.x, w = t >> 6, l = t & 63;
    const int lr = l & 15, lg = l >> 4;

    __shared__ short Ks[32*64];
    __shared__ short Vts[64*32];

    const int qrow = q0 + w*16 + lr;
    const int qc = qrow < SEQ ? qrow : SEQ-1;
    const short* qsrc = qkv + (size_t)(b*SEQ + qc)*NQKV + hh*64;
    bf16x8 xlo = *(const bf16x8*)(qsrc + lg*8);
    bf16x8 xhi = *(const bf16x8*)(qsrc + 32 + lg*8);
    const float4* cp = (const float4*)(cosT + qc*32 + lg*8);
    const float4* sp = (const float4*)(sinT + qc*32 + lg*8);
    float cc[8], sn[8];
    { float4 u = cp[0], v2 = cp[1];
      cc[0]=u.x; cc[1]=u.y; cc[2]=u.z; cc[3]=u.w;
      cc[4]=v2.x; cc[5]=v2.y; cc[6]=v2.z; cc[7]=v2.w; }
    { float4 u = sp[0], v2 = sp[1];
      sn[0]=u.x; sn[1]=u.y; sn[2]=u.z; sn[3]=u.w;
      sn[4]=v2.x; sn[5]=v2.y; sn[6]=v2.z; sn[7]=v2.w; }
    bf16x8 qf0, qf1;
    #pragma unroll
    for (int j = 0; j < 8; ++j) {
        float x1 = bf2f(xlo[j]), x2 = bf2f(xhi[j]);
        qf0[j] = f2bf(x1*cc[j] - x2*sn[j]);
        qf1[j] = f2bf(x2*cc[j] + x1*sn[j]);
    }

    f32x4 oacc[4] = {};
    float mrun = -1e30f, lrun = 0.f;
    const int ntile = min((q0 + 64 + 31) >> 5, 33);
    const float SC = 0.125f * 1.4426950408889634f;  // /sqrt(64) * log2(e)

    const short* kbase = kr + (size_t)bh * SPAD * 64;
    const short* vbase = vt + (size_t)bh * 64 * SPAD;

    const int skrow = t >> 3, skslot = t & 7;
    const int svrow = t >> 2, svslot = t & 3;

    for (int kt = 0; kt < ntile; ++kt) {
        const int kv0 = kt * 32;
        gld_lds16((char*)Ks + (w<<10),
                  (const char*)(kbase + (size_t)(kv0 + skrow)*64) + ((skslot ^ (skrow & 7)) << 4));
        gld_lds16((char*)Vts + (w<<10),
                  (const char*)(vbase + (size_t)svrow*SPAD + kv0) + ((svslot ^ ((svrow>>1) & 3)) << 4));
        __syncthreads();

        f32x4 st0 = {}, st1 = {};
        {
            const int krow = lr;
            const int swz = (krow & 7) << 4;
            const char* kp = (const char*)Ks + krow*128;
            bf16x8 a0 = *(const bf16x8*)(kp + ((lg*16) ^ swz));
            bf16x8 a1 = *(const bf16x8*)(kp + ((64 + lg*16) ^ swz));
            st0 = MFMA16x16(a0, qf0, st0);
            st0 = MFMA16x16(a1, qf1, st0);
        }
        {
            const int krow = 16 + lr;
            const int swz = (krow & 7) << 4;
            const char* kp = (const char*)Ks + krow*128;
            bf16x8 a0 = *(const bf16x8*)(kp + ((lg*16) ^ swz));
            bf16x8 a1 = *(const bf16x8*)(kp + ((64 + lg*16) ^ swz));
            st1 = MFMA16x16(a0, qf0, st1);
            st1 = MFMA16x16(a1, qf1, st1);
        }

        float sv[8];
        float tmax = -1e30f;
        #pragma unroll
        for (int r = 0; r < 4; ++r) {
            int kv = kv0 + lg*4 + r;
            float v = st0[r] * SC;
            v = (kv <= qrow && kv < SEQ) ? v : -1e30f;
            sv[r] = v; tmax = fmaxf(tmax, v);
        }
        #pragma unroll
        for (int r = 0; r < 4; ++r) {
            int kv = kv0 + 16 + lg*4 + r;
            float v = st1[r] * SC;
            v = (kv <= qrow && kv < SEQ) ? v : -1e30f;
            sv[4+r] = v; tmax = fmaxf(tmax, v);
        }
        tmax = fmaxf(tmax, __shfl_xor(tmax, 16, 64));
        tmax = fmaxf(tmax, __shfl_xor(tmax, 32, 64));
        float mnew = fmaxf(mrun, tmax);
        float alpha = exp2f(mrun - mnew);
        float psum = 0.f;
        bf16x8 pf;
        #pragma unroll
        for (int i2 = 0; i2 < 8; ++i2) {
            float p = exp2f(sv[i2] - mnew);
            psum += p;
            pf[i2] = f2bf(p);
        }
        psum += __shfl_xor(psum, 16, 64);
        psum += __shfl_xor(psum, 32, 64);
        lrun = lrun * alpha + psum;
        mrun = mnew;
        #pragma unroll
        for (int df = 0; df < 4; ++df) {
            oacc[df][0] *= alpha; oacc[df][1] *= alpha;
            oacc[df][2] *= alpha; oacc[df][3] *= alpha;
        }
        #pragma unroll
        for (int df = 0; df < 4; ++df) {
            const int vrow = df*16 + lr;
            const int swz = ((vrow >> 1) & 3) << 4;
            const char* vp = (const char*)Vts + vrow*64;
            bf16x4 v0 = *(const bf16x4*)(vp + ((lg*8) ^ swz));
            bf16x4 v1 = *(const bf16x4*)(vp + ((32 + lg*8) ^ swz));
            bf16x8 vf;
            vf[0]=v0[0]; vf[1]=v0[1]; vf[2]=v0[2]; vf[3]=v0[3];
            vf[4]=v1[0]; vf[5]=v1[1]; vf[6]=v1[2]; vf[7]=v1[3];
            oacc[df] = MFMA16x16(vf, pf, oacc[df]);
        }
        __syncthreads();
    }

    if (qrow < SEQ) {
        float inv = 1.0f / lrun;
        short* orow = ob + (size_t)(b*SEQ + qrow)*DIM + hh*64;
        #pragma unroll
        for (int df = 0; df < 4; ++df) {
            bf16x4 ov = { f2bf(oacc[df][0]*inv), f2bf(oacc[df][1]*inv),
                          f2bf(oacc[df][2]*inv), f2bf(oacc[df][3]*inv) };
            *(bf16x4*)(orow + df*16 + lg*4) = ov;
        }
    }
}

extern "C" void kernel_launch(void* const* d_in, const int* in_sizes, int n_in,
                              void* d_out, int out_size, void* d_ws, size_t ws_size,
                              hipStream_t stream) {
    const float* x     = (const float*)d_in[0];
    const float* scale = (const float*)d_in[1];
    const float* w_qkv = (const float*)d_in[2];
    const float* w_out = (const float*)d_in[3];
    float* out = (float*)d_out;

    char* ws = (char*)d_ws;
    size_t off = 0;
    auto alloc = [&](size_t bytes) -> char* {
        char* p = ws + off;
        off += (bytes + 255) & ~(size_t)255;
        return p;
    };
    float* cosT  = (float*)alloc((size_t)SEQ*32*4);
    float* sinT  = (float*)alloc((size_t)SEQ*32*4);
    short* h_b   = (short*)alloc((size_t)MPAD*DIM*2);   // reused as o_b after GEMM1
    short* wq_b  = (short*)alloc((size_t)NQKV*DIM*2);
    short* wo_b  = (short*)alloc((size_t)DIM*DIM*2);
    short* qkv_b = (short*)alloc((size_t)MPAD*NQKV*2);
    short* k_r   = (short*)alloc((size_t)128*SPAD*64*2);
    short* vt    = (short*)alloc((size_t)128*SPAD*64*2);
    short* o_b   = h_b;  // pad rows of h are zeros and stay zeros

    hipFuncSetAttribute((const void*)gemm8p,
                        hipFuncAttributeMaxDynamicSharedMemorySize, 131072);

    trig_k<<<65, 256, 0, stream>>>(cosT, sinT);
    rmsnorm_k<<<MPAD, 256, 0, stream>>>(x, scale, h_b);
    conv_k<<<(NQKV*DIM/4 + 255)/256, 256, 0, stream>>>(w_qkv, wq_b, NQKV*DIM/4);
    conv_k<<<(DIM*DIM/4 + 255)/256, 256, 0, stream>>>(w_out, wo_b, DIM*DIM/4);
    // GEMM1: (MPAD x 2048) x (6144 x 2048)^T -> qkv, 8-phase 256^2 template
    gemm8p<<<(MPAD/256)*(NQKV/256), 512, 131072, stream>>>(h_b, wq_b, qkv_b, NQKV, DIM, MPAD/256);
    rearrange_k<<<128*17, 256, 0, stream>>>(qkv_b, cosT, sinT, k_r, vt);
    attn_k<<<17*128, 256, 0, stream>>>(qkv_b, k_r, vt, cosT, sinT, o_b);
    // GEMM2: out-proj + skip, m97 structure + XCD swizzle
    gemm_bt<<<(MPAD/128)*(DIM/128), 256, 0, stream>>>(o_b, wo_b, out, x, DIM, DIM, MPAD/128);
}

// Round 3
// 436.468 us; speedup vs baseline: 1.1557x; 1.0703x over previous
//
#include <hip/hip_runtime.h>
#include <hip/hip_bf16.h>
#include <cstdint>

#define SEQ   1025
#define SPAD  1088
#define DIM   2048
#define NQKV  6144
#define MROWS 4100   // B*SEQ
#define MPAD  4352   // 17*256
#define NH    32

typedef __attribute__((ext_vector_type(8))) short bf16x8;
typedef __attribute__((ext_vector_type(4))) short bf16x4;
typedef __attribute__((ext_vector_type(4))) float f32x4;

#define MFMA16x16(A,B,C) __builtin_amdgcn_mfma_f32_16x16x32_bf16(A,B,C,0,0,0)

static __device__ __forceinline__ float bf2f(short s) {
    union { unsigned int u; float f; } v;
    v.u = ((unsigned int)(unsigned short)s) << 16;
    return v.f;
}
static __device__ __forceinline__ short f2bf(float f) {
    union { float f; unsigned int u; } v; v.f = f;
    unsigned int r = v.u + 0x7fffu + ((v.u >> 16) & 1u);
    return (short)(r >> 16);
}

typedef __attribute__((address_space(1))) unsigned int u32g;
typedef __attribute__((address_space(3))) unsigned int u32l;
// LDS dest is wave-uniform base; HW adds lane*16 (m104/m108).
static __device__ __forceinline__ void gld_lds16(void* lds, const void* g) {
    __builtin_amdgcn_global_load_lds((const u32g*)(uintptr_t)g,
                                     (u32l*)(uintptr_t)lds, 16, 0, 0);
}

#define SBX() __builtin_amdgcn_sched_barrier(0)
#define PRIO(x) __builtin_amdgcn_s_setprio(x)

// ---------------- RoPE cos/sin table: theta[s][f], f in [0,32) ----------------
__global__ __launch_bounds__(256) void trig_k(float* __restrict__ cosT, float* __restrict__ sinT) {
    int i = blockIdx.x * 256 + threadIdx.x;
    if (i >= SEQ * 16) return;
    int s = i >> 4, f = i & 15;
    float ph = 0.f, pw = 0.f;
    if (s > 0) {
        int p = s - 1;
        ph = -1.f + ((p >> 5) + 0.5f) * 0.0625f;
        pw = -1.f + ((p & 31) + 0.5f) * 0.0625f;
    }
    // freqs = pi * 10^(f/15)
    double fr = 3.141592653589793 * exp((double)f * 0.15350567286626973);
    float th = (float)(ph * fr), tw = (float)(pw * fr);
    cosT[s*32 + f]      = cosf(th);
    sinT[s*32 + f]      = sinf(th);
    cosT[s*32 + 16 + f] = cosf(tw);
    sinT[s*32 + 16 + f] = sinf(tw);
}

// ---------------- RMSNorm fp32 -> bf16, rows >= MROWS zero-filled ----------------
__global__ __launch_bounds__(256) void rmsnorm_k(const float* __restrict__ x,
                                                 const float* __restrict__ sc,
                                                 short* __restrict__ h) {
    int row = blockIdx.x, t = threadIdx.x;
    short* hr = h + (size_t)row * DIM;
    if (row >= MROWS) {
        bf16x8 z = {};
        *(bf16x8*)(hr + t*8) = z;
        return;
    }
    const float4* xr = (const float4*)(x + (size_t)row * DIM);
    float4 a = xr[2*t], b = xr[2*t+1];
    float ss = a.x*a.x + a.y*a.y + a.z*a.z + a.w*a.w
             + b.x*b.x + b.y*b.y + b.z*b.z + b.w*b.w;
    #pragma unroll
    for (int off = 32; off; off >>= 1) ss += __shfl_xor(ss, off, 64);
    __shared__ float red[4];
    if ((t & 63) == 0) red[t >> 6] = ss;
    __syncthreads();
    float ms = (red[0]+red[1]+red[2]+red[3]) * (1.0f/2048.0f);
    float inv = rsqrtf(ms + 1e-6f);
    const float4* sr = (const float4*)sc;
    float4 s0 = sr[2*t], s1 = sr[2*t+1];
    bf16x8 o;
    o[0]=f2bf(a.x*(s0.x*inv)); o[1]=f2bf(a.y*(s0.y*inv));
    o[2]=f2bf(a.z*(s0.z*inv)); o[3]=f2bf(a.w*(s0.w*inv));
    o[4]=f2bf(b.x*(s1.x*inv)); o[5]=f2bf(b.y*(s1.y*inv));
    o[6]=f2bf(b.z*(s1.z*inv)); o[7]=f2bf(b.w*(s1.w*inv));
    *(bf16x8*)(hr + t*8) = o;
}

// ---------------- fp32 -> bf16 weight conversion ----------------
__global__ __launch_bounds__(256) void conv_k(const float* __restrict__ in, short* __restrict__ o, int n4) {
    int i = blockIdx.x * 256 + threadIdx.x;
    if (i >= n4) return;
    float4 v = ((const float4*)in)[i];
    bf16x4 r = { f2bf(v.x), f2bf(v.y), f2bf(v.z), f2bf(v.w) };
    *(bf16x4*)(o + (size_t)i*4) = r;
}

// ================= 8-phase 256x256 GEMM ======================================
// C[m,n] = sum_k A[m,k]*B[n,k], A/B K-inner bf16.  EPI=0: bf16 C.  EPI=1: fp32
// C + skip add, row<MROWS guard.
// 512 thr = 8 waves (2M x 4N), BK=64, LDS 2 x (A 32KB + B 32KB) = 128KB.
// XOR swizzle byte^=(row&7)<<4 both-sides (rule #21).
// Per K-tile (4 phases, 1 barrier each; compiler manages lgkmcnt fine-grained;
// SBX before each closing barrier stops MFMA/read sink past it):
//   ph0: ds_read A-h0(8) + B01(4); MFMA q(0,0); bar
//   ph1: ds_read B23(4);           MFMA q(0,1); bar   [all B + A c0,c2 drained]
//   ph2: stage t+2 {A c0,c2 + B}(6 gld); ds_read A-h1(8); MFMA q(1,1); bar
//   ph3: stage t+2 {A c1,c3}(2 gld); MFMA q(1,0); vmcnt(8); bar
// vmcnt(8) waits tile t+1's 8 loads (issued ~6 phases earlier, ~800cy span);
// the 8 newest (t+2) stay in flight.  Stage into chunk c only after all reads
// of c drained (guaranteed by each wave's data-dep waits + preceding barrier).
template<int EPI>
__global__ __launch_bounds__(512, 2) void gemm8p(const short* __restrict__ A,
                                                 const short* __restrict__ B,
                                                 void* __restrict__ C,
                                                 const float* __restrict__ skip,
                                                 int N, int K, int nbm) {
    extern __shared__ char smem[];
    const int nwg = gridDim.x;            // multiple of 8
    const int cpx = nwg >> 3;
    const int bid = blockIdx.x;
    const int sid = (bid & 7) * cpx + (bid >> 3);   // T1 XCD swizzle (bijective)
    const int bm = sid % nbm;
    const int bn = sid / nbm;

    const int t = threadIdx.x, w = t >> 6, l = t & 63;
    const int lr = l & 15, lg = l >> 4;
    const int wr = w >> 2, wc = w & 3;    // 2M x 4N wave grid

    const short* Ab = A + (size_t)bm * 256 * K;
    const short* Bb = B + (size_t)bn * 256 * K;

    // staging: chunk = 64 rows x 128B (8KB); thread t covers bytes [t*16,+16)
    const int srow = t >> 3;
    const int scol = (((t & 7) ^ (srow & 7)) << 3);   // element offset in row

    // read-side swizzled col offsets (bytes within 128B row), kk = 0,1
    const int cs0 = (lg * 16) ^ ((lr & 7) << 4);
    const int cs1 = (64 + lg * 16) ^ ((lr & 7) << 4);
    const int aRowB = (wr * 128 + lr) * 128;   // + h*8192 + am*2048
    const int bRowB = (wc * 64 + lr) * 128;    // + n*2048

    f32x4 acc[8][4] = {};
    bf16x8 rA[4][2], rB[4][2];

#define STAGE8(kt, bb) do {                                                   \
    const int k0_ = (kt) * 64;                                                \
    _Pragma("unroll")                                                         \
    for (int c = 0; c < 4; ++c) {                                             \
        gld_lds16(smem + (bb)*65536 + c*8192 + (w<<10),                       \
                  Ab + (size_t)(c*64 + srow) * K + k0_ + scol);               \
        gld_lds16(smem + (bb)*65536 + 32768 + c*8192 + (w<<10),               \
                  Bb + (size_t)(c*64 + srow) * K + k0_ + scol);               \
    }                                                                         \
} while (0)

// ph2 stage: A chunks c0,c2 (read-complete after ph0) + all B (after ph1)
#define STAGE_P2(kt, bb) do {                                                 \
    const int k0_ = (kt) * 64;                                                \
    gld_lds16(smem + (bb)*65536 + 0*8192 + (w<<10),                           \
              Ab + (size_t)(0*64 + srow) * K + k0_ + scol);                   \
    gld_lds16(smem + (bb)*65536 + 2*8192 + (w<<10),                           \
              Ab + (size_t)(2*64 + srow) * K + k0_ + scol);                   \
    _Pragma("unroll")                                                         \
    for (int c = 0; c < 4; ++c)                                               \
        gld_lds16(smem + (bb)*65536 + 32768 + c*8192 + (w<<10),               \
                  Bb + (size_t)(c*64 + srow) * K + k0_ + scol);               \
} while (0)

// ph3 stage: A chunks c1,c3 (read-complete after ph2)
#define STAGE_P3(kt, bb) do {                                                 \
    const int k0_ = (kt) * 64;                                                \
    gld_lds16(smem + (bb)*65536 + 1*8192 + (w<<10),                           \
              Ab + (size_t)(1*64 + srow) * K + k0_ + scol);                   \
    gld_lds16(smem + (bb)*65536 + 3*8192 + (w<<10),                           \
              Ab + (size_t)(3*64 + srow) * K + k0_ + scol);                   \
} while (0)

#define READ_A8(bb, h) do {                                                   \
    const char* p_ = smem + (bb)*65536 + aRowB + (h)*8192;                    \
    _Pragma("unroll")                                                         \
    for (int am = 0; am < 4; ++am) {                                          \
        rA[am][0] = *(const bf16x8*)(p_ + am*2048 + cs0);                     \
        rA[am][1] = *(const bf16x8*)(p_ + am*2048 + cs1);                     \
    }                                                                         \
} while (0)

#define READ_B4(bb, np) do {                                                  \
    const char* p_ = smem + (bb)*65536 + 32768 + bRowB + (np)*4096;           \
    _Pragma("unroll")                                                         \
    for (int nn = 0; nn < 2; ++nn) {                                          \
        rB[(np)*2+nn][0] = *(const bf16x8*)(p_ + nn*2048 + cs0);              \
        rB[(np)*2+nn][1] = *(const bf16x8*)(p_ + nn*2048 + cs1);              \
    }                                                                         \
} while (0)

#define MF_Q(h, nh) do {                                                      \
    _Pragma("unroll")                                                         \
    for (int am = 0; am < 4; ++am)                                            \
    _Pragma("unroll")                                                         \
    for (int nn = 0; nn < 2; ++nn) {                                          \
        acc[(h)*4+am][(nh)*2+nn] =                                            \
            MFMA16x16(rA[am][0], rB[(nh)*2+nn][0], acc[(h)*4+am][(nh)*2+nn]); \
        acc[(h)*4+am][(nh)*2+nn] =                                            \
            MFMA16x16(rA[am][1], rB[(nh)*2+nn][1], acc[(h)*4+am][(nh)*2+nn]); \
    }                                                                         \
} while (0)

#define BAR() do { SBX(); __builtin_amdgcn_s_barrier(); } while (0)

    STAGE8(0, 0);
    STAGE8(1, 1);
    asm volatile("s_waitcnt vmcnt(8)" ::: "memory"); SBX();
    __builtin_amdgcn_s_barrier();

    const int NT2 = K / 128;   // iterations, 2 K-tiles each
    for (int it = 0; it < NT2; ++it) {
        const bool more = (it < NT2 - 1);
        // ---- K-tile 2it from buf0 ----
        READ_A8(0, 0); READ_B4(0, 0);
        PRIO(1); MF_Q(0, 0); PRIO(0); BAR();                       // ph0
        READ_B4(0, 1);
        PRIO(1); MF_Q(0, 1); PRIO(0); BAR();                       // ph1
        if (more) STAGE_P2(2*it + 2, 0);
        READ_A8(0, 1);
        PRIO(1); MF_Q(1, 1); PRIO(0); BAR();                       // ph2
        if (more) STAGE_P3(2*it + 2, 0);
        PRIO(1); MF_Q(1, 0); PRIO(0);
        if (more) { asm volatile("s_waitcnt vmcnt(8)" ::: "memory"); }
        else      { asm volatile("s_waitcnt vmcnt(0)" ::: "memory"); }
        BAR();                                                     // ph3
        // ---- K-tile 2it+1 from buf1 ----
        READ_A8(1, 0); READ_B4(1, 0);
        PRIO(1); MF_Q(0, 0); PRIO(0); BAR();                       // ph4
        READ_B4(1, 1);
        PRIO(1); MF_Q(0, 1); PRIO(0); BAR();                       // ph5
        if (more) STAGE_P2(2*it + 3, 1);
        READ_A8(1, 1);
        PRIO(1); MF_Q(1, 1); PRIO(0); BAR();                       // ph6
        if (more) STAGE_P3(2*it + 3, 1);
        PRIO(1); MF_Q(1, 0); PRIO(0);
        if (more) { asm volatile("s_waitcnt vmcnt(8)" ::: "memory"); }
        BAR();                                                     // ph7
    }

    // epilogue: row = bm*256 + wr*128 + m*16 + lg*4 + r, col = bn*256 + wc*64 + n*16 + lr
    #pragma unroll
    for (int m = 0; m < 8; ++m) {
        const int row0 = bm*256 + wr*128 + m*16 + lg*4;
        #pragma unroll
        for (int n = 0; n < 4; ++n) {
            const int col = bn*256 + wc*64 + n*16 + lr;
            #pragma unroll
            for (int r = 0; r < 4; ++r) {
                const int row = row0 + r;
                if constexpr (EPI == 0) {
                    ((short*)C)[(size_t)row * N + col] = f2bf(acc[m][n][r]);
                } else {
                    if (row < MROWS)
                        ((float*)C)[(size_t)row * N + col] =
                            acc[m][n][r] + skip[(size_t)row * N + col];
                }
            }
        }
    }
#undef STAGE8
#undef STAGE_P2
#undef STAGE_P3
#undef READ_A8
#undef READ_B4
#undef MF_Q
#undef BAR
}

// ---------------- K RoPE + scatter to (bh,SPAD,64); V transpose to (bh,64,SPAD) --
__global__ __launch_bounds__(256) void rearrange_k(const short* __restrict__ qkv,
        const float* __restrict__ cosT, const float* __restrict__ sinT,
        short* __restrict__ kr, short* __restrict__ vt) {
    int bid = blockIdx.x;
    int bh = bid / 17, st = bid % 17;
    int b = bh >> 5, hh = bh & 31;
    int s0 = st * 64;
    int t = threadIdx.x;
    __shared__ short vs[64][68];
    #pragma unroll
    for (int i = 0; i < 8; ++i) {
        int task = t + i*256;
        int sl = task >> 5, p = task & 31;
        int s = s0 + sl;
        float y1 = 0.f, y2 = 0.f;
        if (s < SEQ) {
            const short* src = qkv + (size_t)(b*SEQ + s)*NQKV + DIM + hh*64;
            float x1 = bf2f(src[p]), x2 = bf2f(src[32+p]);
            float c = cosT[s*32+p], sn = sinT[s*32+p];
            y1 = x1*c - x2*sn;
            y2 = x2*c + x1*sn;
        }
        short* dst = kr + ((size_t)bh*SPAD + s)*64;
        dst[p]    = f2bf(y1);
        dst[32+p] = f2bf(y2);
    }
    #pragma unroll
    for (int i = 0; i < 16; ++i) {
        int task = t + i*256;
        int sl = task >> 6, d = task & 63;
        int s = s0 + sl;
        short v = 0;
        if (s < SEQ) v = qkv[(size_t)(b*SEQ + s)*NQKV + 2*DIM + hh*64 + d];
        vs[sl][d] = v;
    }
    __syncthreads();
    #pragma unroll
    for (int i = 0; i < 16; ++i) {
        int task = t + i*256;
        int d = task >> 6, sl = task & 63;
        vt[((size_t)bh*64 + d)*SPAD + s0 + sl] = vs[sl][d];
    }
}

// ---------------- Flash attention: 64 q-rows/block, 4 waves x 16 rows ----------
// KVBLK=64: Ks [64 kv][64 d], Vts [64 d][64 kv], both 8KB, XOR-swizzled rows
// (128B).  Swapped QK^T; P stays lane-local; PV uses the 4+4 k-bijection.
__global__ __launch_bounds__(256) void attn_k(const short* __restrict__ qkv,
        const short* __restrict__ kr, const short* __restrict__ vt,
        const float* __restrict__ cosT, const float* __restrict__ sinT,
        short* __restrict__ ob) {
    const int nwg = gridDim.x;              // 2176, multiple of 8
    const int cpx = nwg >> 3;
    const int bid = blockIdx.x;
    const int sid = (bid & 7) * cpx + (bid >> 3);   // T1: blocks sharing bh -> same XCD
    const int bh = sid / 17;
    const int qt = sid % 17;
    const int q0 = qt * 64;
    const int b = bh >> 5, hh = bh & 31;
    const int t = threadIdx.x, w = t >> 6, l = t & 63;
    const int lr = l & 15, lg = l >> 4;

    __shared__ short Ks[64*64];
    __shared__ short Vts[64*64];

    const int qrow = q0 + w*16 + lr;
    const int qc = qrow < SEQ ? qrow : SEQ-1;
    const short* qsrc = qkv + (size_t)(b*SEQ + qc)*NQKV + hh*64;
    bf16x8 xlo = *(const bf16x8*)(qsrc + lg*8);
    bf16x8 xhi = *(const bf16x8*)(qsrc + 32 + lg*8);
    const float4* cp = (const float4*)(cosT + qc*32 + lg*8);
    const float4* sp = (const float4*)(sinT + qc*32 + lg*8);
    float cc[8], sn[8];
    { float4 u = cp[0], v2 = cp[1];
      cc[0]=u.x; cc[1]=u.y; cc[2]=u.z; cc[3]=u.w;
      cc[4]=v2.x; cc[5]=v2.y; cc[6]=v2.z; cc[7]=v2.w; }
    { float4 u = sp[0], v2 = sp[1];
      sn[0]=u.x; sn[1]=u.y; sn[2]=u.z; sn[3]=u.w;
      sn[4]=v2.x; sn[5]=v2.y; sn[6]=v2.z; sn[7]=v2.w; }
    bf16x8 qf0, qf1;
    #pragma unroll
    for (int j = 0; j < 8; ++j) {
        float x1 = bf2f(xlo[j]), x2 = bf2f(xhi[j]);
        qf0[j] = f2bf(x1*cc[j] - x2*sn[j]);
        qf1[j] = f2bf(x2*cc[j] + x1*sn[j]);
    }

    f32x4 oacc[4] = {};
    float mrun = -1e30f, lrun = 0.f;
    const int ntile = qt + 1;
    const float SC = 0.125f * 1.4426950408889634f;  // /sqrt(64) * log2(e)

    const char* kbase = (const char*)(kr + (size_t)bh * SPAD * 64);
    const char* vbase = (const char*)(vt + (size_t)bh * 64 * SPAD);
    const int srow8 = l >> 3;
    const int sslotB = ((l & 7) ^ srow8) << 4;
    const int swz = (lr & 7) << 4;

    for (int kt = 0; kt < ntile; ++kt) {
        const int kv0 = kt * 64;
        // K rows kv0 + w*16 + {0,8} + srow8 ; V rows d = w*16 + {0,8} + srow8
        gld_lds16((char*)Ks + w*2048,
                  kbase + (size_t)(kv0 + w*16 + srow8)*128 + sslotB);
        gld_lds16((char*)Ks + w*2048 + 1024,
                  kbase + (size_t)(kv0 + w*16 + 8 + srow8)*128 + sslotB);
        gld_lds16((char*)Vts + w*2048,
                  vbase + (size_t)(w*16 + srow8)*(SPAD*2) + (size_t)kv0*2 + sslotB);
        gld_lds16((char*)Vts + w*2048 + 1024,
                  vbase + (size_t)(w*16 + 8 + srow8)*(SPAD*2) + (size_t)kv0*2 + sslotB);
        __syncthreads();

        f32x4 st[4];
        #pragma unroll
        for (int f = 0; f < 4; ++f) {
            const char* kp = (const char*)Ks + (f*16 + lr)*128;
            bf16x8 a0 = *(const bf16x8*)(kp + ((lg*16) ^ swz));
            bf16x8 a1 = *(const bf16x8*)(kp + ((64 + lg*16) ^ swz));
            f32x4 z = {};
            z = MFMA16x16(a0, qf0, z);
            st[f] = MFMA16x16(a1, qf1, z);
        }

        float pv[16];
        float tmax = -1e30f;
        #pragma unroll
        for (int f = 0; f < 4; ++f)
        #pragma unroll
        for (int r = 0; r < 4; ++r) {
            int kv = kv0 + f*16 + lg*4 + r;
            float v = st[f][r] * SC;
            v = (kv <= qrow && kv < SEQ) ? v : -1e30f;
            pv[f*4+r] = v; tmax = fmaxf(tmax, v);
        }
        tmax = fmaxf(tmax, __shfl_xor(tmax, 16, 64));
        tmax = fmaxf(tmax, __shfl_xor(tmax, 32, 64));
        float mnew = fmaxf(mrun, tmax);
        float alpha = exp2f(mrun - mnew);
        float psum = 0.f;
        bf16x8 pf0, pf1;
        #pragma unroll
        for (int j = 0; j < 4; ++j) {
            float p0 = exp2f(pv[0*4+j] - mnew);
            float p1 = exp2f(pv[1*4+j] - mnew);
            float p2 = exp2f(pv[2*4+j] - mnew);
            float p3 = exp2f(pv[3*4+j] - mnew);
            psum += (p0 + p1) + (p2 + p3);
            pf0[j] = f2bf(p0); pf0[4+j] = f2bf(p1);
            pf1[j] = f2bf(p2); pf1[4+j] = f2bf(p3);
        }
        psum += __shfl_xor(psum, 16, 64);
        psum += __shfl_xor(psum, 32, 64);
        lrun = lrun * alpha + psum;
        mrun = mnew;
        #pragma unroll
        for (int df = 0; df < 4; ++df) {
            oacc[df][0] *= alpha; oacc[df][1] *= alpha;
            oacc[df][2] *= alpha; oacc[df][3] *= alpha;
        }
        #pragma unroll
        for (int df = 0; df < 4; ++df) {
            const char* vp = (const char*)Vts + (df*16 + lr)*128;
            bf16x4 v0 = *(const bf16x4*)(vp + ((lg*8) ^ swz));
            bf16x4 v1 = *(const bf16x4*)(vp + ((32 + lg*8) ^ swz));
            bf16x4 v2 = *(const bf16x4*)(vp + ((64 + lg*8) ^ swz));
            bf16x4 v3 = *(const bf16x4*)(vp + ((96 + lg*8) ^ swz));
            bf16x8 vf0, vf1;
            vf0[0]=v0[0]; vf0[1]=v0[1]; vf0[2]=v0[2]; vf0[3]=v0[3];
            vf0[4]=v1[0]; vf0[5]=v1[1]; vf0[6]=v1[2]; vf0[7]=v1[3];
            vf1[0]=v2[0]; vf1[1]=v2[1]; vf1[2]=v2[2]; vf1[3]=v2[3];
            vf1[4]=v3[0]; vf1[5]=v3[1]; vf1[6]=v3[2]; vf1[7]=v3[3];
            oacc[df] = MFMA16x16(vf0, pf0, oacc[df]);
            oacc[df] = MFMA16x16(vf1, pf1, oacc[df]);
        }
        __syncthreads();
    }

    if (qrow < SEQ) {
        float inv = 1.0f / lrun;
        short* orow = ob + (size_t)(b*SEQ + qrow)*DIM + hh*64;
        #pragma unroll
        for (int df = 0; df < 4; ++df) {
            bf16x4 ov = { f2bf(oacc[df][0]*inv), f2bf(oacc[df][1]*inv),
                          f2bf(oacc[df][2]*inv), f2bf(oacc[df][3]*inv) };
            *(bf16x4*)(orow + df*16 + lg*4) = ov;
        }
    }
}

extern "C" void kernel_launch(void* const* d_in, const int* in_sizes, int n_in,
                              void* d_out, int out_size, void* d_ws, size_t ws_size,
                              hipStream_t stream) {
    const float* x     = (const float*)d_in[0];
    const float* scale = (const float*)d_in[1];
    const float* w_qkv = (const float*)d_in[2];
    const float* w_out = (const float*)d_in[3];
    float* out = (float*)d_out;

    char* ws = (char*)d_ws;
    size_t off = 0;
    auto alloc = [&](size_t bytes) -> char* {
        char* p = ws + off;
        off += (bytes + 255) & ~(size_t)255;
        return p;
    };
    float* cosT  = (float*)alloc((size_t)SEQ*32*4);
    float* sinT  = (float*)alloc((size_t)SEQ*32*4);
    short* h_b   = (short*)alloc((size_t)MPAD*DIM*2);   // reused as o_b after GEMM1
    short* wq_b  = (short*)alloc((size_t)NQKV*DIM*2);
    short* wo_b  = (short*)alloc((size_t)DIM*DIM*2);
    short* qkv_b = (short*)alloc((size_t)MPAD*NQKV*2);
    short* k_r   = (short*)alloc((size_t)128*SPAD*64*2);
    short* vt    = (short*)alloc((size_t)128*SPAD*64*2);
    short* o_b   = h_b;  // rmsnorm zeroed pad rows; attn writes only rows < MROWS

    hipFuncSetAttribute((const void*)gemm8p<0>,
                        hipFuncAttributeMaxDynamicSharedMemorySize, 131072);
    hipFuncSetAttribute((const void*)gemm8p<1>,
                        hipFuncAttributeMaxDynamicSharedMemorySize, 131072);

    trig_k<<<65, 256, 0, stream>>>(cosT, sinT);
    rmsnorm_k<<<MPAD, 256, 0, stream>>>(x, scale, h_b);
    conv_k<<<(NQKV*DIM/4 + 255)/256, 256, 0, stream>>>(w_qkv, wq_b, NQKV*DIM/4);
    conv_k<<<(DIM*DIM/4 + 255)/256, 256, 0, stream>>>(w_out, wo_b, DIM*DIM/4);
    // GEMM1: (MPAD x 2048) x (6144 x 2048)^T -> qkv
    gemm8p<0><<<(MPAD/256)*(NQKV/256), 512, 131072, stream>>>(h_b, wq_b, qkv_b, nullptr, NQKV, DIM, MPAD/256);
    rearrange_k<<<128*17, 256, 0, stream>>>(qkv_b, cosT, sinT, k_r, vt);
    attn_k<<<17*128, 256, 0, stream>>>(qkv_b, k_r, vt, cosT, sinT, o_b);
    // GEMM2: out-proj + skip (fp32), same 8-phase template
    gemm8p<1><<<(MPAD/256)*(DIM/256), 512, 131072, stream>>>(o_b, wo_b, out, x, DIM, DIM, MPAD/256);
}